// Round 9
// baseline (5235.528 us; speedup 1.0000x reference)
//
#include <hip/hip_runtime.h>
#include <hip/hip_bf16.h>

// Round 9: OUTPUT BUFFER IS FLOAT32 (reference outputs are jnp.float32).
// Rounds 0-8 all ran fresh; the sole output bug was writing bf16 into the f32
// buffer (zq_p's u16 writes even landed inside output-0's f32 region,
// producing the constant 1.092911e-03). This round: identical pipeline, all
// three outputs written as f32.
// B=16, CH=256, RES=16 (256 px/sample), E=32, NEMB=1024, NP=128, L=4,
// CP=CN=1024, BETA=0.25, EPS=1e-5.
// Outputs (f32, concat): out[1048576] | loss[1] | zq_p[4194304].

__device__ __forceinline__ float silu_r9(float x){ return x / (1.f + expf(-x)); }
__device__ __forceinline__ float b2f_r9(__hip_bfloat16 v){ return __bfloat162float(v); }
__device__ __forceinline__ float ldv_r9(const void* p, int i, int f32m){
  if (f32m) return ((const float*)p)[i];
  return b2f_r9(((const __hip_bfloat16*)p)[i]);
}

// ---------------- workspace layout (float offsets), total 9.57 MB ----------------
#define FLAGS_OFF 0
#define LOSS_OFF  4
#define STATS_OFF 8
#define CB32_OFF  128        // 1024x32 f32
#define CBN_OFF   32896      // 1024
#define IDXP_OFF  33984      // 131072 int
#define IDXN_OFF  165056     // 131072 int
#define R2_OFF    296192     // lnp (16,128,256) -> hcat_p
#define R3_OFF    820480     // lnn (16,128,256) -> hcat_n
#define R1_OFF    1344768    // h (16,256,256) / z chunks (4,1024,256) / R chunks

#define CS_R9 4              // samples per chunk

// ---------------- input dtype probe + zero accumulators ----------------
__global__ __launch_bounds__(256) void detect_r9(const void* cbv, float* flags, float* lossacc){
  __shared__ int bad;
  if (threadIdx.x == 0) bad = 0;
  __syncthreads();
  const unsigned short* u = (const unsigned short*)cbv;
  int local = 0;
  for (int i = threadIdx.x; i < 32768; i += 256){
    unsigned e = (u[i] >> 7) & 0xFF;   // bf16 exponent field
    if (e >= 126) local = 1;           // true bf16 codebook values are ~2^-10
  }
  if (local) bad = 1;
  __syncthreads();
  if (threadIdx.x == 0){
    flags[0] = bad ? 1.f : 0.f;        // 1.0 => inputs are f32
    lossacc[0] = 0.f; lossacc[1] = 0.f;
  }
}

// ---------------- codebook -> f32 + |c|^2 ----------------
__global__ __launch_bounds__(256) void cbprep_r9(const void* cbv, const float* flags,
                                                 float* cb32, float* cbn){
  const int f32m = (flags[0] != 0.f);
  int j = blockIdx.x * 256 + threadIdx.x;
  if (j < 1024){
    float s = 0.f;
    for (int e = 0; e < 32; ++e){
      float v = ldv_r9(cbv, j*32 + e, f32m);
      cb32[j*32 + e] = v;
      s += v*v;
    }
    cbn[j] = s;
  }
}

// ---------------- tiled GEMM: out[b,o,p] = act(sum_c W[o,c]*In[b,c,p] + bias[o]) ----
// INMODE: 0 = f32 raw, 2 = dual-dtype + silu (x input), 4 = two-half f32 + silu
template<int KDIM, int INMODE, bool OUTSILU>
__global__ __launch_bounds__(256) void gemm_r9(
    const float* __restrict__ inF, const float* __restrict__ inF2,
    const void* __restrict__ inV,
    const void* __restrict__ W, const void* __restrict__ bias,
    float* __restrict__ outF,
    const float* __restrict__ flags,
    int OUTC, int o_off, int b_base, int ib_sub, int ob_sub)
{
  __shared__ float As[32][64];
  __shared__ float Bs[32][68];

  const int f32m = (flags[0] != 0.f);
  const int t  = threadIdx.x;
  const int q0 = (blockIdx.x << 6) + (b_base << 8);
  const int b  = q0 >> 8;          // global sample
  const int p0 = q0 & 255;
  const int o0 = blockIdx.y << 6;
  const int tx = t & 15, ty = t >> 4;
  float acc[4][4] = {};

  for (int k0 = 0; k0 < KDIM; k0 += 32){
    if constexpr (INMODE == 2){
      if (f32m){
        const float* xf = (const float*)inV;
        #pragma unroll
        for (int r = 0; r < 8; ++r){
          int ii = t + (r << 8); int cc = ii >> 6, px = ii & 63;
          As[cc][px] = silu_r9(xf[((b*KDIM + k0 + cc) << 8) + p0 + px]);
        }
      } else {
        const __hip_bfloat16* xb = (const __hip_bfloat16*)inV;
        #pragma unroll
        for (int r = 0; r < 8; ++r){
          int ii = t + (r << 8); int cc = ii >> 6, px = ii & 63;
          As[cc][px] = silu_r9(b2f_r9(xb[((b*KDIM + k0 + cc) << 8) + p0 + px]));
        }
      }
    } else if constexpr (INMODE == 4){
      const float* src = (k0 < 128) ? inF : inF2;
      const int kh = k0 & 127;
      #pragma unroll
      for (int r = 0; r < 8; ++r){
        int ii = t + (r << 8); int cc = ii >> 6, px = ii & 63;
        As[cc][px] = silu_r9(src[((b*128 + kh + cc) << 8) + p0 + px]);
      }
    } else {  // INMODE 0
      #pragma unroll
      for (int r = 0; r < 8; ++r){
        int ii = t + (r << 8); int cc = ii >> 6, px = ii & 63;
        As[cc][px] = inF[(((b - ib_sub)*KDIM + k0 + cc) << 8) + p0 + px];
      }
    }
    if (f32m){
      const float* Wf = (const float*)W;
      #pragma unroll
      for (int r = 0; r < 8; ++r){
        int ii = t + (r << 8); int oo = ii >> 5, cc = ii & 31;
        Bs[cc][oo] = Wf[(o0 + oo)*KDIM + k0 + cc];
      }
    } else {
      const __hip_bfloat16* Wb = (const __hip_bfloat16*)W;
      #pragma unroll
      for (int r = 0; r < 8; ++r){
        int ii = t + (r << 8); int oo = ii >> 5, cc = ii & 31;
        Bs[cc][oo] = b2f_r9(Wb[(o0 + oo)*KDIM + k0 + cc]);
      }
    }
    __syncthreads();
    #pragma unroll
    for (int kk = 0; kk < 32; ++kk){
      const float4 a = *reinterpret_cast<const float4*>(&As[kk][tx << 2]);
      const float4 w = *reinterpret_cast<const float4*>(&Bs[kk][ty << 2]);
      acc[0][0] += w.x*a.x; acc[0][1] += w.x*a.y; acc[0][2] += w.x*a.z; acc[0][3] += w.x*a.w;
      acc[1][0] += w.y*a.x; acc[1][1] += w.y*a.y; acc[1][2] += w.y*a.z; acc[1][3] += w.y*a.w;
      acc[2][0] += w.z*a.x; acc[2][1] += w.z*a.y; acc[2][2] += w.z*a.z; acc[2][3] += w.z*a.w;
      acc[3][0] += w.w*a.x; acc[3][1] += w.w*a.y; acc[3][2] += w.w*a.z; acc[3][3] += w.w*a.w;
    }
    __syncthreads();
  }
  #pragma unroll
  for (int i = 0; i < 4; ++i){
    const int o = o0 + (ty << 2) + i;
    const float bb = ldv_r9(bias, o, f32m);
    const int base = (((b - ob_sub)*OUTC + o_off + o) << 8) + p0 + (tx << 2);
    float v0 = acc[i][0] + bb, v1 = acc[i][1] + bb, v2 = acc[i][2] + bb, v3 = acc[i][3] + bb;
    if constexpr (OUTSILU){ v0 = silu_r9(v0); v1 = silu_r9(v1); v2 = silu_r9(v2); v3 = silu_r9(v3); }
    *reinterpret_cast<float4*>(&outF[base]) = make_float4(v0, v1, v2, v3);
  }
}

// ---------------- per-sample LN stats over silu(h_half) ----------------
__global__ __launch_bounds__(256) void stats_r9(const float* __restrict__ h, float* __restrict__ stats){
  const int b = blockIdx.x >> 1, half = blockIdx.x & 1;
  const float* base = h + ((b*256 + half*128) << 8);
  float s = 0.f, s2 = 0.f;
  for (int i = threadIdx.x; i < 32768; i += 256){
    float a = silu_r9(base[i]);
    s += a; s2 += a*a;
  }
  __shared__ float sh[2][256];
  sh[0][threadIdx.x] = s; sh[1][threadIdx.x] = s2;
  __syncthreads();
  for (int st = 128; st > 0; st >>= 1){
    if (threadIdx.x < st){
      sh[0][threadIdx.x] += sh[0][threadIdx.x + st];
      sh[1][threadIdx.x] += sh[1][threadIdx.x + st];
    }
    __syncthreads();
  }
  if (threadIdx.x == 0){
    float mu  = sh[0][0] * (1.f/32768.f);
    float var = sh[1][0] * (1.f/32768.f) - mu*mu;
    stats[half*32 + b]      = mu;
    stats[half*32 + 16 + b] = 1.f / sqrtf(var + 1e-5f);
  }
}

// ---------------- LN apply ----------------
__global__ __launch_bounds__(256) void ln_r9(const float* __restrict__ h,
    const void* lwp, const void* lbp, const void* lwn, const void* lbn,
    const float* __restrict__ stats, const float* __restrict__ flags,
    float* __restrict__ lnp, float* __restrict__ lnn){
  const int f32m = (flags[0] != 0.f);
  int i = blockIdx.x * 256 + threadIdx.x;
  int b = i >> 16, c = (i >> 8) & 255, p = i & 255;
  float a = silu_r9(h[i]);
  if (c < 128){
    float v = (a - stats[b]) * stats[16 + b] * ldv_r9(lwp, (c << 8) + p, f32m) + ldv_r9(lbp, (c << 8) + p, f32m);
    lnp[((b*128 + c) << 8) + p] = v;
  } else {
    int cc = c - 128;
    float v = (a - stats[32 + b]) * stats[48 + b] * ldv_r9(lwn, (cc << 8) + p, f32m) + ldv_r9(lbn, (cc << 8) + p, f32m);
    lnn[((b*128 + cc) << 8) + p] = v;
  }
}

// ---------------- VQ search over a 4-sample chunk ----------------
// phylo (LEVELS=4): w = n*4+l, components z[bl, e*32 + l*8 + kp, p], n = kp*256+p
// non-phylo (LEVELS=1): w = kp*256+p, components z[bl, e*32 + kp, p]
template<int LEVELS>
__global__ __launch_bounds__(256) void quant_r9(const float* __restrict__ z,
    const float* __restrict__ cb32, const float* __restrict__ cbn,
    int* __restrict__ idxout, float* __restrict__ lossacc, int b_base){
  const int g = blockIdx.x * 256 + threadIdx.x;
  const int part = g & 3;
  const int vidl = g >> 2;
  const int bl = vidl >> 13;
  const int w  = vidl & 8191;
  int p, cbase;
  if (LEVELS == 4){
    int l = w & 3, n = w >> 2;
    p = n & 255; cbase = (l << 3) + (n >> 8);
  } else {
    p = w & 255; cbase = w >> 8;
  }
  float zv[32]; float zn = 0.f;
  #pragma unroll
  for (int e = 0; e < 32; ++e){
    float v = z[((bl*1024 + (e << 5) + cbase) << 8) + p];
    zv[e] = v; zn += v*v;
  }
  float best = __builtin_inff(); int bi = 0;
  const int j0 = part << 8;
  for (int j = j0; j < j0 + 256; ++j){
    float dot = 0.f;
    #pragma unroll
    for (int e = 0; e < 32; ++e) dot += zv[e] * cb32[(j << 5) + e];
    float d = (zn - 2.f*dot) + cbn[j];
    if (d < best){ best = d; bi = j; }
  }
  #pragma unroll
  for (int k = 2; k > 0; k >>= 1){
    float od = __shfl_down(best, k);
    int   oj = __shfl_down(bi, k);
    if (od < best || (od == best && oj < bi)){ best = od; bi = oj; }
  }
  if (part == 0) idxout[(bl + b_base)*8192 + w] = bi;
  __shared__ float sh[256];
  sh[threadIdx.x] = (part == 0) ? best : 0.f;
  __syncthreads();
  for (int st = 128; st > 0; st >>= 1){
    if (threadIdx.x < st) sh[threadIdx.x] += sh[threadIdx.x + st];
    __syncthreads();
  }
  if (threadIdx.x == 0) atomicAdd(lossacc, sh[0]);
}

// ---------------- materialize R = reshape_out(zq) for a 4-sample chunk ----------------
// flat t = bl*2^18 + c'*256 + p; c' = e*32 + l*8 + kp (L=4) or e*32 + kp (L=1)
template<int LEVELS>
__global__ __launch_bounds__(256) void rmat_r9(const int* __restrict__ idx,
    const float* __restrict__ cb32, float* __restrict__ R, int b_base){
  int t = blockIdx.x * 256 + threadIdx.x;   // over 4*1024*256 = 1048576
  int p  = t & 255;
  int cp = (t >> 8) & 1023;
  int bl = t >> 18;                         // sample span = 2^18
  int e   = cp >> 5;
  int rem = cp & 31;
  int id;
  if (LEVELS == 4){
    int l = rem >> 3, kp = rem & 7;
    id = idx[(b_base + bl)*8192 + (((kp << 8) + p) << 2) + l];
  } else {
    id = idx[(b_base + bl)*8192 + (rem << 8) + p];
  }
  R[t] = cb32[((id & 1023) << 5) + e];      // mask: fault-proof, free when valid
}

// ---------------- zq_p output: (16,32,2048,4) FLOAT32 ----------------
__global__ __launch_bounds__(256) void zqout_r9(const int* __restrict__ idxp,
    const float* __restrict__ cb32, float* __restrict__ out){
  int t = blockIdx.x * 256 + threadIdx.x;
  int l = t & 3, n = (t >> 2) & 2047, e = (t >> 13) & 31, b = t >> 18;
  int id = idxp[b*8192 + (n << 2) + l];
  out[t] = cb32[((id & 1023) << 5) + e];
}

// ---------------- loss finalize (FLOAT32) ----------------
__global__ void loss_r9(const float* __restrict__ lossacc, float* __restrict__ out){
  if (threadIdx.x == 0 && blockIdx.x == 0)
    out[0] = 1.25f * (lossacc[0] + lossacc[1]) * (1.f/4194304.f);
}

extern "C" void kernel_launch(void* const* d_in, const int* in_sizes, int n_in,
                              void* d_out, int out_size, void* d_ws, size_t ws_size,
                              hipStream_t stream){
  (void)in_sizes; (void)n_in; (void)out_size; (void)ws_size;
  const void* x   = d_in[0];
  const void* ciw = d_in[1];
  const void* cib = d_in[2];
  const void* lwp = d_in[3];
  const void* lbp = d_in[4];
  const void* wpi = d_in[5];
  const void* bpi = d_in[6];
  const void* wpo = d_in[7];
  const void* bpo = d_in[8];
  const void* lwn = d_in[9];
  const void* lbn = d_in[10];
  const void* wni = d_in[11];
  const void* bni = d_in[12];
  const void* wno = d_in[13];
  const void* bno = d_in[14];
  const void* cbk = d_in[15];
  const void* cow = d_in[16];
  const void* cob = d_in[17];

  float* ws    = (float*)d_ws;
  float* flags = ws + FLAGS_OFF;
  float* loss  = ws + LOSS_OFF;
  float* stats = ws + STATS_OFF;
  float* cb32  = ws + CB32_OFF;
  float* cbn   = ws + CBN_OFF;
  int*   idxp  = (int*)(ws + IDXP_OFF);
  int*   idxn  = (int*)(ws + IDXN_OFF);
  float* R2    = ws + R2_OFF;
  float* R3    = ws + R3_OFF;
  float* R1    = ws + R1_OFF;

  float* outO = (float*)d_out;            // out: f32 [1048576]
  float* outL = outO + 1048576;           // loss: f32 [1]
  float* outZ = outO + 1048577;           // zq_p: f32 [4194304]

  detect_r9<<<1, 256, 0, stream>>>(cbk, flags, loss);
  cbprep_r9<<<4, 256, 0, stream>>>(cbk, flags, cb32, cbn);
  // h = conv_in(silu(x)) -> R1
  gemm_r9<256,2,false><<<dim3(64,4), 256, 0, stream>>>(
      nullptr, nullptr, x, ciw, cib, R1, flags, 256, 0, 0, 0, 0);
  stats_r9<<<32, 256, 0, stream>>>(R1, stats);
  ln_r9<<<4096, 256, 0, stream>>>(R1, lwp, lbp, lwn, lbn, stats, flags, R2, R3);
  // phylo: z chunks (R2 -> R1), quantize
  for (int c = 0; c < 16; c += CS_R9){
    gemm_r9<128,0,true><<<dim3(CS_R9*4,16), 256, 0, stream>>>(
        R2, nullptr, nullptr, wpi, bpi, R1, flags, 1024, 0, c, 0, c);
    quant_r9<4><<<CS_R9*128, 256, 0, stream>>>(R1, cb32, cbn, idxp, loss + 0, c);
  }
  // non-phylo: z chunks (R3 -> R1), quantize
  for (int c = 0; c < 16; c += CS_R9){
    gemm_r9<128,0,true><<<dim3(CS_R9*4,16), 256, 0, stream>>>(
        R3, nullptr, nullptr, wni, bni, R1, flags, 1024, 0, c, 0, c);
    quant_r9<1><<<CS_R9*128, 256, 0, stream>>>(R1, cb32, cbn, idxn, loss + 1, c);
  }
  zqout_r9<<<16384, 256, 0, stream>>>(idxp, cb32, outZ);
  // hout_p: materialize R chunk, GEMM -> R2 rows (lnp dead)
  for (int c = 0; c < 16; c += CS_R9){
    rmat_r9<4><<<4096, 256, 0, stream>>>(idxp, cb32, R1, c);
    gemm_r9<1024,0,true><<<dim3(CS_R9*4,2), 256, 0, stream>>>(
        R1, nullptr, nullptr, wpo, bpo, R2, flags, 128, 0, c, c, 0);
  }
  // hout_n: same into R3 (lnn dead)
  for (int c = 0; c < 16; c += CS_R9){
    rmat_r9<1><<<4096, 256, 0, stream>>>(idxn, cb32, R1, c);
    gemm_r9<1024,0,true><<<dim3(CS_R9*4,2), 256, 0, stream>>>(
        R1, nullptr, nullptr, wno, bno, R3, flags, 128, 0, c, c, 0);
  }
  // out = conv_out(silu(hcat)) -> f32 output
  gemm_r9<256,4,false><<<dim3(64,4), 256, 0, stream>>>(
      R2, R3, nullptr, cow, cob, outO, flags, 256, 0, 0, 0, 0);
  loss_r9<<<1, 64, 0, stream>>>(loss, outL);
}

// Round 10
// 1000.081 us; speedup vs baseline: 5.2351x; 5.2351x over previous
//
#include <hip/hip_runtime.h>
#include <hip/hip_bf16.h>

// Round 10: quant rewrite (the 3.8ms/5.2ms bottleneck; was VALUBusy=8%,
// VGPR=32 => zv[32] spilled). New quant: VPT=2 vectors/thread in explicit
// float4 regs, 2-way code-split across lane pairs, codebook tiles in LDS,
// strict-ascending argmin (np semantics), same f32 rounding as r9 (passed).
// Also: ws_size-gated full-batch (CS=16) cuts 58 dispatches -> 16.
// Outputs (f32, concat): out[1048576] | loss[1] | zq_p[4194304].

__device__ __forceinline__ float silu_rt(float x){ return x / (1.f + expf(-x)); }
__device__ __forceinline__ float b2f_rt(__hip_bfloat16 v){ return __bfloat162float(v); }
__device__ __forceinline__ float ldv_rt(const void* p, int i, int f32m){
  if (f32m) return ((const float*)p)[i];
  return b2f_rt(((const __hip_bfloat16*)p)[i]);
}

// ---------------- workspace layout (float offsets) ----------------
#define FLAGS_OFF 0
#define LOSS_OFF  4
#define STATS_OFF 8
#define CB32_OFF  128        // 1024x32 f32
#define CBN_OFF   32896      // 1024
#define IDXP_OFF  33984      // 131072 int
#define IDXN_OFF  165056     // 131072 int
#define R2_OFF    296192     // lnp (16,128,256) -> hcat_p
#define R3_OFF    820480     // lnn (16,128,256) -> hcat_n
#define R1_OFF    1344768    // h (16,256,256) / z (CS,1024,256) / R (CS,1024,256)

// ---------------- input dtype probe + zero accumulators ----------------
__global__ __launch_bounds__(256) void detect_rt(const void* cbv, float* flags, float* lossacc){
  __shared__ int bad;
  if (threadIdx.x == 0) bad = 0;
  __syncthreads();
  const unsigned short* u = (const unsigned short*)cbv;
  int local = 0;
  for (int i = threadIdx.x; i < 32768; i += 256){
    unsigned e = (u[i] >> 7) & 0xFF;
    if (e >= 126) local = 1;
  }
  if (local) bad = 1;
  __syncthreads();
  if (threadIdx.x == 0){
    flags[0] = bad ? 1.f : 0.f;   // 1.0 => inputs are f32
    lossacc[0] = 0.f; lossacc[1] = 0.f;
  }
}

// ---------------- codebook -> f32 + |c|^2 ----------------
__global__ __launch_bounds__(256) void cbprep_rt(const void* cbv, const float* flags,
                                                 float* cb32, float* cbn){
  const int f32m = (flags[0] != 0.f);
  int j = blockIdx.x * 256 + threadIdx.x;
  if (j < 1024){
    float s = 0.f;
    for (int e = 0; e < 32; ++e){
      float v = ldv_rt(cbv, j*32 + e, f32m);
      cb32[j*32 + e] = v;
      s += v*v;
    }
    cbn[j] = s;
  }
}

// ---------------- tiled GEMM (unchanged from r9, which passed) ----------------
template<int KDIM, int INMODE, bool OUTSILU>
__global__ __launch_bounds__(256) void gemm_rt(
    const float* __restrict__ inF, const float* __restrict__ inF2,
    const void* __restrict__ inV,
    const void* __restrict__ W, const void* __restrict__ bias,
    float* __restrict__ outF,
    const float* __restrict__ flags,
    int OUTC, int o_off, int b_base, int ib_sub, int ob_sub)
{
  __shared__ float As[32][64];
  __shared__ float Bs[32][68];

  const int f32m = (flags[0] != 0.f);
  const int t  = threadIdx.x;
  const int q0 = (blockIdx.x << 6) + (b_base << 8);
  const int b  = q0 >> 8;
  const int p0 = q0 & 255;
  const int o0 = blockIdx.y << 6;
  const int tx = t & 15, ty = t >> 4;
  float acc[4][4] = {};

  for (int k0 = 0; k0 < KDIM; k0 += 32){
    if constexpr (INMODE == 2){
      if (f32m){
        const float* xf = (const float*)inV;
        #pragma unroll
        for (int r = 0; r < 8; ++r){
          int ii = t + (r << 8); int cc = ii >> 6, px = ii & 63;
          As[cc][px] = silu_rt(xf[((b*KDIM + k0 + cc) << 8) + p0 + px]);
        }
      } else {
        const __hip_bfloat16* xb = (const __hip_bfloat16*)inV;
        #pragma unroll
        for (int r = 0; r < 8; ++r){
          int ii = t + (r << 8); int cc = ii >> 6, px = ii & 63;
          As[cc][px] = silu_rt(b2f_rt(xb[((b*KDIM + k0 + cc) << 8) + p0 + px]));
        }
      }
    } else if constexpr (INMODE == 4){
      const float* src = (k0 < 128) ? inF : inF2;
      const int kh = k0 & 127;
      #pragma unroll
      for (int r = 0; r < 8; ++r){
        int ii = t + (r << 8); int cc = ii >> 6, px = ii & 63;
        As[cc][px] = silu_rt(src[((b*128 + kh + cc) << 8) + p0 + px]);
      }
    } else {
      #pragma unroll
      for (int r = 0; r < 8; ++r){
        int ii = t + (r << 8); int cc = ii >> 6, px = ii & 63;
        As[cc][px] = inF[(((b - ib_sub)*KDIM + k0 + cc) << 8) + p0 + px];
      }
    }
    if (f32m){
      const float* Wf = (const float*)W;
      #pragma unroll
      for (int r = 0; r < 8; ++r){
        int ii = t + (r << 8); int oo = ii >> 5, cc = ii & 31;
        Bs[cc][oo] = Wf[(o0 + oo)*KDIM + k0 + cc];
      }
    } else {
      const __hip_bfloat16* Wb = (const __hip_bfloat16*)W;
      #pragma unroll
      for (int r = 0; r < 8; ++r){
        int ii = t + (r << 8); int oo = ii >> 5, cc = ii & 31;
        Bs[cc][oo] = b2f_rt(Wb[(o0 + oo)*KDIM + k0 + cc]);
      }
    }
    __syncthreads();
    #pragma unroll
    for (int kk = 0; kk < 32; ++kk){
      const float4 a = *reinterpret_cast<const float4*>(&As[kk][tx << 2]);
      const float4 w = *reinterpret_cast<const float4*>(&Bs[kk][ty << 2]);
      acc[0][0] += w.x*a.x; acc[0][1] += w.x*a.y; acc[0][2] += w.x*a.z; acc[0][3] += w.x*a.w;
      acc[1][0] += w.y*a.x; acc[1][1] += w.y*a.y; acc[1][2] += w.y*a.z; acc[1][3] += w.y*a.w;
      acc[2][0] += w.z*a.x; acc[2][1] += w.z*a.y; acc[2][2] += w.z*a.z; acc[2][3] += w.z*a.w;
      acc[3][0] += w.w*a.x; acc[3][1] += w.w*a.y; acc[3][2] += w.w*a.z; acc[3][3] += w.w*a.w;
    }
    __syncthreads();
  }
  #pragma unroll
  for (int i = 0; i < 4; ++i){
    const int o = o0 + (ty << 2) + i;
    const float bb = ldv_rt(bias, o, f32m);
    const int base = (((b - ob_sub)*OUTC + o_off + o) << 8) + p0 + (tx << 2);
    float v0 = acc[i][0] + bb, v1 = acc[i][1] + bb, v2 = acc[i][2] + bb, v3 = acc[i][3] + bb;
    if constexpr (OUTSILU){ v0 = silu_rt(v0); v1 = silu_rt(v1); v2 = silu_rt(v2); v3 = silu_rt(v3); }
    *reinterpret_cast<float4*>(&outF[base]) = make_float4(v0, v1, v2, v3);
  }
}

// ---------------- per-sample LN stats over silu(h_half) ----------------
__global__ __launch_bounds__(256) void stats_rt(const float* __restrict__ h, float* __restrict__ stats){
  const int b = blockIdx.x >> 1, half = blockIdx.x & 1;
  const float* base = h + ((b*256 + half*128) << 8);
  float s = 0.f, s2 = 0.f;
  for (int i = threadIdx.x; i < 32768; i += 256){
    float a = silu_rt(base[i]);
    s += a; s2 += a*a;
  }
  __shared__ float sh[2][256];
  sh[0][threadIdx.x] = s; sh[1][threadIdx.x] = s2;
  __syncthreads();
  for (int st = 128; st > 0; st >>= 1){
    if (threadIdx.x < st){
      sh[0][threadIdx.x] += sh[0][threadIdx.x + st];
      sh[1][threadIdx.x] += sh[1][threadIdx.x + st];
    }
    __syncthreads();
  }
  if (threadIdx.x == 0){
    float mu  = sh[0][0] * (1.f/32768.f);
    float var = sh[1][0] * (1.f/32768.f) - mu*mu;
    stats[half*32 + b]      = mu;
    stats[half*32 + 16 + b] = 1.f / sqrtf(var + 1e-5f);
  }
}

// ---------------- LN apply ----------------
__global__ __launch_bounds__(256) void ln_rt(const float* __restrict__ h,
    const void* lwp, const void* lbp, const void* lwn, const void* lbn,
    const float* __restrict__ stats, const float* __restrict__ flags,
    float* __restrict__ lnp, float* __restrict__ lnn){
  const int f32m = (flags[0] != 0.f);
  int i = blockIdx.x * 256 + threadIdx.x;
  int b = i >> 16, c = (i >> 8) & 255, p = i & 255;
  float a = silu_rt(h[i]);
  if (c < 128){
    float v = (a - stats[b]) * stats[16 + b] * ldv_rt(lwp, (c << 8) + p, f32m) + ldv_rt(lbp, (c << 8) + p, f32m);
    lnp[((b*128 + c) << 8) + p] = v;
  } else {
    int cc = c - 128;
    float v = (a - stats[32 + b]) * stats[48 + b] * ldv_rt(lwn, (cc << 8) + p, f32m) + ldv_rt(lbn, (cc << 8) + p, f32m);
    lnn[((b*128 + cc) << 8) + p] = v;
  }
}

// ---------------- VQ search v2 ----------------
// Dispatch covers CS samples (z chunk-local). threads = CS*8192.
// pt = gid&1 (code-range part), vbase = gid>>1; vid0 = vbase, vid1 = vbase + CS*4096
// (sample-aligned: same w/p/cbase, bl1 = bl0 + CS/2). Part pt scans
// j = t*256 + pt*128 + i (t=tile, i=0..127): ascending within part; lane-pair
// combine prefers smaller d then smaller j  => exact np first-argmin.
template<int LEVELS>
__global__ __launch_bounds__(256) void quant_rt(const float* __restrict__ z,
    const float* __restrict__ cb32, const float* __restrict__ cbn,
    int* __restrict__ idxout, float* __restrict__ lossacc, int b_base, int CS){
  __shared__ float4 cbT[2048];     // 256 codes x 32 dims (32 KB)
  __shared__ float  cbnS[1024];    // |c|^2 (4 KB)
  __shared__ float  red[256];

  const int tid = threadIdx.x;
  const int gid = blockIdx.x * 256 + tid;
  const int pt = gid & 1;
  const int vbase = gid >> 1;
  const int halfstride = CS << 12;             // CS*4096
  const int vid0 = vbase, vid1 = vbase + halfstride;

  const int bl0 = vid0 >> 13, bl1 = vid1 >> 13;
  const int w = vid0 & 8191;                   // == vid1 & 8191 (sample-aligned)
  int p, cbase;
  if (LEVELS == 4){
    int l = w & 3, n = w >> 2;
    p = n & 255; cbase = (l << 3) + (n >> 8);
  } else {
    p = w & 255; cbase = w >> 8;
  }

  // stage |c|^2 once
  #pragma unroll
  for (int q = 0; q < 4; ++q) cbnS[tid + (q << 8)] = cbn[tid + (q << 8)];

  // load the two z vectors into registers (float4 regs; same rounding as r9)
  float4 za[8], zb[8];
  float zn0 = 0.f, zn1 = 0.f;
  const int zoff = ((bl0 << 10) + cbase) << 8;
  const int zoff1 = ((bl1 << 10) + cbase) << 8;
  #pragma unroll
  for (int e4 = 0; e4 < 8; ++e4){
    float4 a, b;
    a.x = z[zoff  + (((e4<<2)+0) << 13) + p];
    a.y = z[zoff  + (((e4<<2)+1) << 13) + p];
    a.z = z[zoff  + (((e4<<2)+2) << 13) + p];
    a.w = z[zoff  + (((e4<<2)+3) << 13) + p];
    b.x = z[zoff1 + (((e4<<2)+0) << 13) + p];
    b.y = z[zoff1 + (((e4<<2)+1) << 13) + p];
    b.z = z[zoff1 + (((e4<<2)+2) << 13) + p];
    b.w = z[zoff1 + (((e4<<2)+3) << 13) + p];
    za[e4] = a; zb[e4] = b;
    zn0 += a.x*a.x; zn0 += a.y*a.y; zn0 += a.z*a.z; zn0 += a.w*a.w;
    zn1 += b.x*b.x; zn1 += b.y*b.y; zn1 += b.z*b.z; zn1 += b.w*b.w;
  }

  float best0 = __builtin_inff(), best1 = __builtin_inff();
  int bi0 = 0, bi1 = 0;

  for (int t = 0; t < 4; ++t){
    __syncthreads();
    // stage tile t: 2048 float4 (coalesced)
    const float4* g4 = reinterpret_cast<const float4*>(cb32) + (t << 11);
    #pragma unroll
    for (int r = 0; r < 8; ++r) cbT[tid + (r << 8)] = g4[tid + (r << 8)];
    __syncthreads();

    const int jloc0 = pt << 7;                 // 0 or 128 within tile
    #pragma unroll 2
    for (int i = 0; i < 128; ++i){
      const int jl = jloc0 + i;
      const int j  = (t << 8) + jl;
      const float4* c = &cbT[jl << 3];
      float dot0 = 0.f, dot1 = 0.f;
      #pragma unroll
      for (int e4 = 0; e4 < 8; ++e4){
        const float4 cc = c[e4];
        dot0 = fmaf(za[e4].x, cc.x, dot0); dot1 = fmaf(zb[e4].x, cc.x, dot1);
        dot0 = fmaf(za[e4].y, cc.y, dot0); dot1 = fmaf(zb[e4].y, cc.y, dot1);
        dot0 = fmaf(za[e4].z, cc.z, dot0); dot1 = fmaf(zb[e4].z, cc.z, dot1);
        dot0 = fmaf(za[e4].w, cc.w, dot0); dot1 = fmaf(zb[e4].w, cc.w, dot1);
      }
      const float cn = cbnS[j];
      const float d0 = (zn0 - 2.f*dot0) + cn;
      const float d1 = (zn1 - 2.f*dot1) + cn;
      if (d0 < best0){ best0 = d0; bi0 = j; }
      if (d1 < best1){ best1 = d1; bi1 = j; }
    }
  }

  // combine lane pair (parts): smaller d wins; tie -> smaller j (np argmin)
  {
    float od0 = __shfl_down(best0, 1); int oj0 = __shfl_down(bi0, 1);
    float od1 = __shfl_down(best1, 1); int oj1 = __shfl_down(bi1, 1);
    if (od0 < best0 || (od0 == best0 && oj0 < bi0)){ best0 = od0; bi0 = oj0; }
    if (od1 < best1 || (od1 == best1 && oj1 < bi1)){ best1 = od1; bi1 = oj1; }
  }
  if (pt == 0){
    idxout[(b_base + bl0)*8192 + w] = bi0;
    idxout[(b_base + bl1)*8192 + w] = bi1;
  }
  red[tid] = (pt == 0) ? (best0 + best1) : 0.f;
  __syncthreads();
  for (int st = 128; st > 0; st >>= 1){
    if (tid < st) red[tid] += red[tid + st];
    __syncthreads();
  }
  if (tid == 0) atomicAdd(lossacc, red[0]);
}

// ---------------- materialize R = reshape_out(zq) ----------------
template<int LEVELS>
__global__ __launch_bounds__(256) void rmat_rt(const int* __restrict__ idx,
    const float* __restrict__ cb32, float* __restrict__ R, int b_base){
  int t = blockIdx.x * 256 + threadIdx.x;
  int p  = t & 255;
  int cp = (t >> 8) & 1023;
  int bl = t >> 18;
  int e   = cp >> 5;
  int rem = cp & 31;
  int id;
  if (LEVELS == 4){
    int l = rem >> 3, kp = rem & 7;
    id = idx[(b_base + bl)*8192 + (((kp << 8) + p) << 2) + l];
  } else {
    id = idx[(b_base + bl)*8192 + (rem << 8) + p];
  }
  R[t] = cb32[((id & 1023) << 5) + e];
}

// ---------------- zq_p output: (16,32,2048,4) f32 ----------------
__global__ __launch_bounds__(256) void zqout_rt(const int* __restrict__ idxp,
    const float* __restrict__ cb32, float* __restrict__ out){
  int t = blockIdx.x * 256 + threadIdx.x;
  int l = t & 3, n = (t >> 2) & 2047, e = (t >> 13) & 31, b = t >> 18;
  int id = idxp[b*8192 + (n << 2) + l];
  out[t] = cb32[((id & 1023) << 5) + e];
}

// ---------------- loss finalize ----------------
__global__ void loss_rt(const float* __restrict__ lossacc, float* __restrict__ out){
  if (threadIdx.x == 0 && blockIdx.x == 0)
    out[0] = 1.25f * (lossacc[0] + lossacc[1]) * (1.f/4194304.f);
}

extern "C" void kernel_launch(void* const* d_in, const int* in_sizes, int n_in,
                              void* d_out, int out_size, void* d_ws, size_t ws_size,
                              hipStream_t stream){
  (void)in_sizes; (void)n_in; (void)out_size;
  const void* x   = d_in[0];
  const void* ciw = d_in[1];
  const void* cib = d_in[2];
  const void* lwp = d_in[3];
  const void* lbp = d_in[4];
  const void* wpi = d_in[5];
  const void* bpi = d_in[6];
  const void* wpo = d_in[7];
  const void* bpo = d_in[8];
  const void* lwn = d_in[9];
  const void* lbn = d_in[10];
  const void* wni = d_in[11];
  const void* bni = d_in[12];
  const void* wno = d_in[13];
  const void* bno = d_in[14];
  const void* cbk = d_in[15];
  const void* cow = d_in[16];
  const void* cob = d_in[17];

  float* ws    = (float*)d_ws;
  float* flags = ws + FLAGS_OFF;
  float* loss  = ws + LOSS_OFF;
  float* stats = ws + STATS_OFF;
  float* cb32  = ws + CB32_OFF;
  float* cbn   = ws + CBN_OFF;
  int*   idxp  = (int*)(ws + IDXP_OFF);
  int*   idxn  = (int*)(ws + IDXN_OFF);
  float* R2    = ws + R2_OFF;
  float* R3    = ws + R3_OFF;
  float* R1    = ws + R1_OFF;

  float* outO = (float*)d_out;
  float* outL = outO + 1048576;
  float* outZ = outO + 1048577;

  // ws-gated chunk size (host-constant => graph-safe). r9 proved >= 9.57 MB.
  const size_t wsf = ws_size / 4;
  int CS = 4;
  if      (wsf >= (size_t)R1_OFF + 16u*262144u) CS = 16;
  else if (wsf >= (size_t)R1_OFF +  8u*262144u) CS = 8;

  detect_rt<<<1, 256, 0, stream>>>(cbk, flags, loss);
  cbprep_rt<<<4, 256, 0, stream>>>(cbk, flags, cb32, cbn);
  gemm_rt<256,2,false><<<dim3(64,4), 256, 0, stream>>>(
      nullptr, nullptr, x, ciw, cib, R1, flags, 256, 0, 0, 0, 0);
  stats_rt<<<32, 256, 0, stream>>>(R1, stats);
  ln_rt<<<4096, 256, 0, stream>>>(R1, lwp, lbp, lwn, lbn, stats, flags, R2, R3);
  // phylo: z chunks (R2 -> R1), quantize
  for (int c = 0; c < 16; c += CS){
    gemm_rt<128,0,true><<<dim3(CS*4,16), 256, 0, stream>>>(
        R2, nullptr, nullptr, wpi, bpi, R1, flags, 1024, 0, c, 0, c);
    quant_rt<4><<<CS*32, 256, 0, stream>>>(R1, cb32, cbn, idxp, loss + 0, c, CS);
  }
  // non-phylo
  for (int c = 0; c < 16; c += CS){
    gemm_rt<128,0,true><<<dim3(CS*4,16), 256, 0, stream>>>(
        R3, nullptr, nullptr, wni, bni, R1, flags, 1024, 0, c, 0, c);
    quant_rt<1><<<CS*32, 256, 0, stream>>>(R1, cb32, cbn, idxn, loss + 1, c, CS);
  }
  zqout_rt<<<16384, 256, 0, stream>>>(idxp, cb32, outZ);
  // hout_p: R chunk -> GEMM -> R2 (lnp dead)
  for (int c = 0; c < 16; c += CS){
    rmat_rt<4><<<CS*1024, 256, 0, stream>>>(idxp, cb32, R1, c);
    gemm_rt<1024,0,true><<<dim3(CS*4,2), 256, 0, stream>>>(
        R1, nullptr, nullptr, wpo, bpo, R2, flags, 128, 0, c, c, 0);
  }
  // hout_n -> R3 (lnn dead)
  for (int c = 0; c < 16; c += CS){
    rmat_rt<1><<<CS*1024, 256, 0, stream>>>(idxn, cb32, R1, c);
    gemm_rt<1024,0,true><<<dim3(CS*4,2), 256, 0, stream>>>(
        R1, nullptr, nullptr, wno, bno, R3, flags, 128, 0, c, c, 0);
  }
  gemm_rt<256,4,false><<<dim3(64,4), 256, 0, stream>>>(
      R2, R3, nullptr, cow, cob, outO, flags, 256, 0, 0, 0, 0);
  loss_rt<<<1, 64, 0, stream>>>(loss, outL);
}

// Round 11
// 649.206 us; speedup vs baseline: 8.0645x; 1.5405x over previous
//
#include <hip/hip_runtime.h>
#include <hip/hip_bf16.h>

// Round 11: GEMM occupancy fixes. r10 counters: hout GEMMs (128 blocks) at
// 182us, occupancy 6%, VALUBusy 5% -> latency-bound from tiny grids.
// gemm2: 32x64 tiles (2x blocks), hout = fused idx-gather + split-K x4 with
// f32 atomics (bias+silu folded into final conv staging). z-GEMM keeps exact
// ascending-k f32 order (argmin gaps ~4e-8: no dtype/order changes upstream
// of quant). quant (r10, verified) untouched.
// Outputs (f32): out[1048576] | loss[1] | zq_p[4194304].

__device__ __forceinline__ float silu_rv(float x){ return x / (1.f + expf(-x)); }
__device__ __forceinline__ float b2f_rv(__hip_bfloat16 v){ return __bfloat162float(v); }
__device__ __forceinline__ float ldv_rv(const void* p, int i, int f32m){
  if (f32m) return ((const float*)p)[i];
  return b2f_rv(((const __hip_bfloat16*)p)[i]);
}

// ---------------- workspace layout (float offsets) ----------------
#define FLAGS_OFF 0
#define LOSS_OFF  4
#define STATS_OFF 8
#define CB32_OFF  128        // 1024x32 f32
#define CBN_OFF   32896      // 1024
#define IDXP_OFF  33984      // 131072 int
#define IDXN_OFF  165056     // 131072 int
#define R2_OFF    296192     // lnp -> hcat_p accum (524288)
#define R3_OFF    820480     // lnn -> hcat_n accum (524288)
#define R1_OFF    1344768    // h (1048576) / z chunks (CS*262144)

// ---------------- input dtype probe + zero accumulators ----------------
__global__ __launch_bounds__(256) void detect_rv(const void* cbv, float* flags, float* lossacc){
  __shared__ int bad;
  if (threadIdx.x == 0) bad = 0;
  __syncthreads();
  const unsigned short* u = (const unsigned short*)cbv;
  int local = 0;
  for (int i = threadIdx.x; i < 32768; i += 256){
    unsigned e = (u[i] >> 7) & 0xFF;
    if (e >= 126) local = 1;
  }
  if (local) bad = 1;
  __syncthreads();
  if (threadIdx.x == 0){
    flags[0] = bad ? 1.f : 0.f;   // 1.0 => inputs are f32
    lossacc[0] = 0.f; lossacc[1] = 0.f;
  }
}

// ---------------- codebook -> f32 + |c|^2 ----------------
__global__ __launch_bounds__(256) void cbprep_rv(const void* cbv, const float* flags,
                                                 float* cb32, float* cbn){
  const int f32m = (flags[0] != 0.f);
  int j = blockIdx.x * 256 + threadIdx.x;
  if (j < 1024){
    float s = 0.f;
    for (int e = 0; e < 32; ++e){
      float v = ldv_rv(cbv, j*32 + e, f32m);
      cb32[j*32 + e] = v;
      s += v*v;
    }
    cbn[j] = s;
  }
}

// ---------------- gemm2: 32px x 64out tiles, 256 threads ----------------
// out[b,o,p] = act(sum_c W[o,c]*In[b,c,p] + bias[o])
// INMODE: 0 = f32 raw, 2 = dual-dtype + silu (x), 3 = idx-gather (hout),
//         5 = two-half raw + staging-bias + silu (final conv)
// ATOMIC: split-K partial -> atomicAdd, no bias/act.
// Thread map: tx=t&15 -> px = tx*2 (2 px); ty=t>>4 -> o = ty*4 (4 outs).
template<int KCH, int INMODE, bool OUTSILU, bool ATOMIC, int LEVELS>
__global__ __launch_bounds__(256) void gemm2_rv(
    const float* __restrict__ inF, const float* __restrict__ inF2,
    const void* __restrict__ inV,
    const void* __restrict__ W, const void* __restrict__ biasO,
    const void* __restrict__ sbA, const void* __restrict__ sbB,
    const int* __restrict__ idxin, const float* __restrict__ cb32,
    float* __restrict__ outF, const float* __restrict__ flags,
    int KDIM, int OUTC, int o_off, int b_base, int ib_sub, int ob_sub)
{
  __shared__ float As[32][32];
  __shared__ float Bs[32][68];
  __shared__ int   IdxS[32][32];

  const int f32m = (flags[0] != 0.f);
  const int t  = threadIdx.x;
  const int q0 = (blockIdx.x << 5) + (b_base << 8);
  const int b  = q0 >> 8;
  const int p0 = q0 & 255;
  const int o0 = blockIdx.y << 6;
  const int k0base = blockIdx.z * KCH;
  const int tx = t & 15, ty = t >> 4;
  float acc[4][2] = {};

  // staging thread map for As: ch = t>>3, px4 = (t&7)*4 (4 consecutive px)
  const int sch = t >> 3, spx = (t & 7) << 2;

  if constexpr (INMODE == 3){
    // IdxS[ch][px]: 1024 entries, 4 per thread (same map)
    #pragma unroll
    for (int j = 0; j < 4; ++j){
      const int p = p0 + spx + j;
      if constexpr (LEVELS == 4){
        const int l = sch >> 3, kp = sch & 7;
        IdxS[sch][spx + j] = idxin[b*8192 + (((kp << 8) + p) << 2) + l];
      } else {
        IdxS[sch][spx + j] = idxin[b*8192 + (sch << 8) + p];
      }
    }
    __syncthreads();
  }

  for (int kc = 0; kc < KCH; kc += 32){
    const int k0 = k0base + kc;
    // ---- stage As (32ch x 32px) ----
    if constexpr (INMODE == 0){
      const float4 v = *reinterpret_cast<const float4*>(
          &inF[(((b - ib_sub)*KDIM + k0 + sch) << 8) + p0 + spx]);
      *reinterpret_cast<float4*>(&As[sch][spx]) = v;
    } else if constexpr (INMODE == 2){
      if (f32m){
        const float* xf = (const float*)inV;
        float4 v = *reinterpret_cast<const float4*>(&xf[((b*KDIM + k0 + sch) << 8) + p0 + spx]);
        v.x = silu_rv(v.x); v.y = silu_rv(v.y); v.z = silu_rv(v.z); v.w = silu_rv(v.w);
        *reinterpret_cast<float4*>(&As[sch][spx]) = v;
      } else {
        const __hip_bfloat16* xb = (const __hip_bfloat16*)inV;
        const int off = ((b*KDIM + k0 + sch) << 8) + p0 + spx;
        #pragma unroll
        for (int j = 0; j < 4; ++j) As[sch][spx + j] = silu_rv(b2f_rv(xb[off + j]));
      }
    } else if constexpr (INMODE == 3){
      const int e = k0 >> 5;
      #pragma unroll
      for (int j = 0; j < 4; ++j)
        As[sch][spx + j] = cb32[((IdxS[sch][spx + j] & 1023) << 5) + e];
    } else { // INMODE 5
      const float* src = (k0 < 128) ? inF : inF2;
      const void* sb   = (k0 < 128) ? sbA : sbB;
      const int kh = k0 & 127;
      const float bb = ldv_rv(sb, kh + sch, f32m);
      float4 v = *reinterpret_cast<const float4*>(&src[((b*128 + kh + sch) << 8) + p0 + spx]);
      v.x = silu_rv(v.x + bb); v.y = silu_rv(v.y + bb);
      v.z = silu_rv(v.z + bb); v.w = silu_rv(v.w + bb);
      *reinterpret_cast<float4*>(&As[sch][spx]) = v;
    }
    // ---- stage Bs (32ch x 64out) ----
    if (f32m){
      const float* Wf = (const float*)W;
      #pragma unroll
      for (int r = 0; r < 8; ++r){
        int ii = t + (r << 8); int oo = ii >> 5, cc = ii & 31;
        Bs[cc][oo] = Wf[(o0 + oo)*KDIM + k0 + cc];
      }
    } else {
      const __hip_bfloat16* Wb = (const __hip_bfloat16*)W;
      #pragma unroll
      for (int r = 0; r < 8; ++r){
        int ii = t + (r << 8); int oo = ii >> 5, cc = ii & 31;
        Bs[cc][oo] = b2f_rv(Wb[(o0 + oo)*KDIM + k0 + cc]);
      }
    }
    __syncthreads();
    #pragma unroll
    for (int kk = 0; kk < 32; ++kk){
      const float2 a = *reinterpret_cast<const float2*>(&As[kk][tx << 1]);
      const float4 w = *reinterpret_cast<const float4*>(&Bs[kk][ty << 2]);
      acc[0][0] += w.x*a.x; acc[0][1] += w.x*a.y;
      acc[1][0] += w.y*a.x; acc[1][1] += w.y*a.y;
      acc[2][0] += w.z*a.x; acc[2][1] += w.z*a.y;
      acc[3][0] += w.w*a.x; acc[3][1] += w.w*a.y;
    }
    __syncthreads();
  }
  #pragma unroll
  for (int i = 0; i < 4; ++i){
    const int o = o0 + (ty << 2) + i;
    const int base = (((b - ob_sub)*OUTC + o_off + o) << 8) + p0 + (tx << 1);
    if constexpr (ATOMIC){
      atomicAdd(&outF[base + 0], acc[i][0]);
      atomicAdd(&outF[base + 1], acc[i][1]);
    } else {
      const float bb = ldv_rv(biasO, o, f32m);
      float v0 = acc[i][0] + bb, v1 = acc[i][1] + bb;
      if constexpr (OUTSILU){ v0 = silu_rv(v0); v1 = silu_rv(v1); }
      *reinterpret_cast<float2*>(&outF[base]) = make_float2(v0, v1);
    }
  }
}

// ---------------- per-sample LN stats over silu(h_half) ----------------
__global__ __launch_bounds__(256) void stats_rv(const float* __restrict__ h, float* __restrict__ stats){
  const int b = blockIdx.x >> 1, half = blockIdx.x & 1;
  const float* base = h + ((b*256 + half*128) << 8);
  float s = 0.f, s2 = 0.f;
  for (int i = threadIdx.x; i < 32768; i += 256){
    float a = silu_rv(base[i]);
    s += a; s2 += a*a;
  }
  __shared__ float sh[2][256];
  sh[0][threadIdx.x] = s; sh[1][threadIdx.x] = s2;
  __syncthreads();
  for (int st = 128; st > 0; st >>= 1){
    if (threadIdx.x < st){
      sh[0][threadIdx.x] += sh[0][threadIdx.x + st];
      sh[1][threadIdx.x] += sh[1][threadIdx.x + st];
    }
    __syncthreads();
  }
  if (threadIdx.x == 0){
    float mu  = sh[0][0] * (1.f/32768.f);
    float var = sh[1][0] * (1.f/32768.f) - mu*mu;
    stats[half*32 + b]      = mu;
    stats[half*32 + 16 + b] = 1.f / sqrtf(var + 1e-5f);
  }
}

// ---------------- LN apply ----------------
__global__ __launch_bounds__(256) void ln_rv(const float* __restrict__ h,
    const void* lwp, const void* lbp, const void* lwn, const void* lbn,
    const float* __restrict__ stats, const float* __restrict__ flags,
    float* __restrict__ lnp, float* __restrict__ lnn){
  const int f32m = (flags[0] != 0.f);
  int i = blockIdx.x * 256 + threadIdx.x;
  int b = i >> 16, c = (i >> 8) & 255, p = i & 255;
  float a = silu_rv(h[i]);
  if (c < 128){
    float v = (a - stats[b]) * stats[16 + b] * ldv_rv(lwp, (c << 8) + p, f32m) + ldv_rv(lbp, (c << 8) + p, f32m);
    lnp[((b*128 + c) << 8) + p] = v;
  } else {
    int cc = c - 128;
    float v = (a - stats[32 + b]) * stats[48 + b] * ldv_rv(lwn, (cc << 8) + p, f32m) + ldv_rv(lbn, (cc << 8) + p, f32m);
    lnn[((b*128 + cc) << 8) + p] = v;
  }
}

// ---------------- VQ search (r10, verified) ----------------
template<int LEVELS>
__global__ __launch_bounds__(256) void quant_rv(const float* __restrict__ z,
    const float* __restrict__ cb32, const float* __restrict__ cbn,
    int* __restrict__ idxout, float* __restrict__ lossacc, int b_base, int CS){
  __shared__ float4 cbT[2048];
  __shared__ float  cbnS[1024];
  __shared__ float  red[256];

  const int tid = threadIdx.x;
  const int gid = blockIdx.x * 256 + tid;
  const int pt = gid & 1;
  const int vbase = gid >> 1;
  const int halfstride = CS << 12;
  const int vid0 = vbase, vid1 = vbase + halfstride;

  const int bl0 = vid0 >> 13, bl1 = vid1 >> 13;
  const int w = vid0 & 8191;
  int p, cbase;
  if (LEVELS == 4){
    int l = w & 3, n = w >> 2;
    p = n & 255; cbase = (l << 3) + (n >> 8);
  } else {
    p = w & 255; cbase = w >> 8;
  }

  #pragma unroll
  for (int q = 0; q < 4; ++q) cbnS[tid + (q << 8)] = cbn[tid + (q << 8)];

  float4 za[8], zb[8];
  float zn0 = 0.f, zn1 = 0.f;
  const int zoff = ((bl0 << 10) + cbase) << 8;
  const int zoff1 = ((bl1 << 10) + cbase) << 8;
  #pragma unroll
  for (int e4 = 0; e4 < 8; ++e4){
    float4 a, b;
    a.x = z[zoff  + (((e4<<2)+0) << 13) + p];
    a.y = z[zoff  + (((e4<<2)+1) << 13) + p];
    a.z = z[zoff  + (((e4<<2)+2) << 13) + p];
    a.w = z[zoff  + (((e4<<2)+3) << 13) + p];
    b.x = z[zoff1 + (((e4<<2)+0) << 13) + p];
    b.y = z[zoff1 + (((e4<<2)+1) << 13) + p];
    b.z = z[zoff1 + (((e4<<2)+2) << 13) + p];
    b.w = z[zoff1 + (((e4<<2)+3) << 13) + p];
    za[e4] = a; zb[e4] = b;
    zn0 += a.x*a.x; zn0 += a.y*a.y; zn0 += a.z*a.z; zn0 += a.w*a.w;
    zn1 += b.x*b.x; zn1 += b.y*b.y; zn1 += b.z*b.z; zn1 += b.w*b.w;
  }

  float best0 = __builtin_inff(), best1 = __builtin_inff();
  int bi0 = 0, bi1 = 0;

  for (int t = 0; t < 4; ++t){
    __syncthreads();
    const float4* g4 = reinterpret_cast<const float4*>(cb32) + (t << 11);
    #pragma unroll
    for (int r = 0; r < 8; ++r) cbT[tid + (r << 8)] = g4[tid + (r << 8)];
    __syncthreads();

    const int jloc0 = pt << 7;
    #pragma unroll 2
    for (int i = 0; i < 128; ++i){
      const int jl = jloc0 + i;
      const int j  = (t << 8) + jl;
      const float4* c = &cbT[jl << 3];
      float dot0 = 0.f, dot1 = 0.f;
      #pragma unroll
      for (int e4 = 0; e4 < 8; ++e4){
        const float4 cc = c[e4];
        dot0 = fmaf(za[e4].x, cc.x, dot0); dot1 = fmaf(zb[e4].x, cc.x, dot1);
        dot0 = fmaf(za[e4].y, cc.y, dot0); dot1 = fmaf(zb[e4].y, cc.y, dot1);
        dot0 = fmaf(za[e4].z, cc.z, dot0); dot1 = fmaf(zb[e4].z, cc.z, dot1);
        dot0 = fmaf(za[e4].w, cc.w, dot0); dot1 = fmaf(zb[e4].w, cc.w, dot1);
      }
      const float cn = cbnS[j];
      const float d0 = (zn0 - 2.f*dot0) + cn;
      const float d1 = (zn1 - 2.f*dot1) + cn;
      if (d0 < best0){ best0 = d0; bi0 = j; }
      if (d1 < best1){ best1 = d1; bi1 = j; }
    }
  }

  {
    float od0 = __shfl_down(best0, 1); int oj0 = __shfl_down(bi0, 1);
    float od1 = __shfl_down(best1, 1); int oj1 = __shfl_down(bi1, 1);
    if (od0 < best0 || (od0 == best0 && oj0 < bi0)){ best0 = od0; bi0 = oj0; }
    if (od1 < best1 || (od1 == best1 && oj1 < bi1)){ best1 = od1; bi1 = oj1; }
  }
  if (pt == 0){
    idxout[(b_base + bl0)*8192 + w] = bi0;
    idxout[(b_base + bl1)*8192 + w] = bi1;
  }
  red[tid] = (pt == 0) ? (best0 + best1) : 0.f;
  __syncthreads();
  for (int st = 128; st > 0; st >>= 1){
    if (tid < st) red[tid] += red[tid + st];
    __syncthreads();
  }
  if (tid == 0) atomicAdd(lossacc, red[0]);
}

// ---------------- zq_p output (f32) ----------------
__global__ __launch_bounds__(256) void zqout_rv(const int* __restrict__ idxp,
    const float* __restrict__ cb32, float* __restrict__ out){
  int t = blockIdx.x * 256 + threadIdx.x;
  int l = t & 3, n = (t >> 2) & 2047, e = (t >> 13) & 31, b = t >> 18;
  int id = idxp[b*8192 + (n << 2) + l];
  out[t] = cb32[((id & 1023) << 5) + e];
}

// ---------------- zero hcat accum ----------------
__global__ __launch_bounds__(256) void zero_rv(float* __restrict__ p){
  p[blockIdx.x * 256 + threadIdx.x] = 0.f;
}

// ---------------- loss finalize ----------------
__global__ void loss_rv(const float* __restrict__ lossacc, float* __restrict__ out){
  if (threadIdx.x == 0 && blockIdx.x == 0)
    out[0] = 1.25f * (lossacc[0] + lossacc[1]) * (1.f/4194304.f);
}

extern "C" void kernel_launch(void* const* d_in, const int* in_sizes, int n_in,
                              void* d_out, int out_size, void* d_ws, size_t ws_size,
                              hipStream_t stream){
  (void)in_sizes; (void)n_in; (void)out_size;
  const void* x   = d_in[0];
  const void* ciw = d_in[1];
  const void* cib = d_in[2];
  const void* lwp = d_in[3];
  const void* lbp = d_in[4];
  const void* wpi = d_in[5];
  const void* bpi = d_in[6];
  const void* wpo = d_in[7];
  const void* bpo = d_in[8];
  const void* lwn = d_in[9];
  const void* lbn = d_in[10];
  const void* wni = d_in[11];
  const void* bni = d_in[12];
  const void* wno = d_in[13];
  const void* bno = d_in[14];
  const void* cbk = d_in[15];
  const void* cow = d_in[16];
  const void* cob = d_in[17];

  float* ws    = (float*)d_ws;
  float* flags = ws + FLAGS_OFF;
  float* loss  = ws + LOSS_OFF;
  float* stats = ws + STATS_OFF;
  float* cb32  = ws + CB32_OFF;
  float* cbn   = ws + CBN_OFF;
  int*   idxp  = (int*)(ws + IDXP_OFF);
  int*   idxn  = (int*)(ws + IDXN_OFF);
  float* R2    = ws + R2_OFF;
  float* R3    = ws + R3_OFF;
  float* R1    = ws + R1_OFF;

  float* outO = (float*)d_out;
  float* outL = outO + 1048576;
  float* outZ = outO + 1048577;

  const size_t wsf = ws_size / 4;
  int CS = 4;
  if      (wsf >= (size_t)R1_OFF + 16u*262144u) CS = 16;
  else if (wsf >= (size_t)R1_OFF +  8u*262144u) CS = 8;

  detect_rv<<<1, 256, 0, stream>>>(cbk, flags, loss);
  cbprep_rv<<<4, 256, 0, stream>>>(cbk, flags, cb32, cbn);
  // h = conv_in(silu(x)) -> R1   (512 blocks)
  gemm2_rv<256,2,false,false,0><<<dim3(128,4), 256, 0, stream>>>(
      nullptr, nullptr, x, ciw, cib, nullptr, nullptr, nullptr, nullptr,
      R1, flags, 256, 256, 0, 0, 0, 0);
  stats_rv<<<32, 256, 0, stream>>>(R1, stats);
  ln_rv<<<4096, 256, 0, stream>>>(R1, lwp, lbp, lwn, lbn, stats, flags, R2, R3);
  // phylo: z chunks (R2 -> R1), quantize
  for (int c = 0; c < 16; c += CS){
    gemm2_rv<128,0,true,false,0><<<dim3(CS*8,16), 256, 0, stream>>>(
        R2, nullptr, nullptr, wpi, bpi, nullptr, nullptr, nullptr, nullptr,
        R1, flags, 128, 1024, 0, c, 0, c);
    quant_rv<4><<<CS*32, 256, 0, stream>>>(R1, cb32, cbn, idxp, loss + 0, c, CS);
  }
  // non-phylo
  for (int c = 0; c < 16; c += CS){
    gemm2_rv<128,0,true,false,0><<<dim3(CS*8,16), 256, 0, stream>>>(
        R3, nullptr, nullptr, wni, bni, nullptr, nullptr, nullptr, nullptr,
        R1, flags, 128, 1024, 0, c, 0, c);
    quant_rv<1><<<CS*32, 256, 0, stream>>>(R1, cb32, cbn, idxn, loss + 1, c, CS);
  }
  zqout_rv<<<16384, 256, 0, stream>>>(idxp, cb32, outZ);
  // hcat accum := 0 (R2|R3 contiguous 1048576 floats)
  zero_rv<<<4096, 256, 0, stream>>>(R2);
  // hout_p: fused gather + split-K x4, atomic accum into R2 (1024 blocks)
  gemm2_rv<256,3,false,true,4><<<dim3(128,2,4), 256, 0, stream>>>(
      nullptr, nullptr, nullptr, wpo, nullptr, nullptr, nullptr, idxp, cb32,
      R2, flags, 1024, 128, 0, 0, 0, 0);
  // hout_n -> R3
  gemm2_rv<256,3,false,true,1><<<dim3(128,2,4), 256, 0, stream>>>(
      nullptr, nullptr, nullptr, wno, nullptr, nullptr, nullptr, idxn, cb32,
      R3, flags, 1024, 128, 0, 0, 0, 0);
  // out = conv_out(silu(hcat + hout_bias))   (512 blocks)
  gemm2_rv<256,5,false,false,0><<<dim3(128,4), 256, 0, stream>>>(
      R2, R3, nullptr, cow, cob, bpo, bno, nullptr, nullptr,
      outO, flags, 256, 256, 0, 0, 0, 0);
  loss_rv<<<1, 64, 0, stream>>>(loss, outL);
}

// Round 12
// 630.164 us; speedup vs baseline: 8.3082x; 1.0302x over previous
//
#include <hip/hip_runtime.h>
#include <hip/hip_bf16.h>

// Round 12: quant LDS fix. r11 counters: quant 178us, SQ_LDS_BANK_CONFLICT
// 3.46e7 (pt-split addresses 128 codes apart == same bank group; +4cyc per
// ds_read_b128), grid 128 blocks at CS=4 (half chip idle). Now: 8-way code
// split (512 blocks at CS=4) + bank-skewed LDS layout (8 disjoint 4-bank
// groups) -> conflict-free, 2 blocks/CU. Argmin semantics (first-min, (d,j)
// lexicographic) preserved exactly. All other kernels unchanged from r11.
// Outputs (f32): out[1048576] | loss[1] | zq_p[4194304].

__device__ __forceinline__ float silu_rw(float x){ return x / (1.f + expf(-x)); }
__device__ __forceinline__ float b2f_rw(__hip_bfloat16 v){ return __bfloat162float(v); }
__device__ __forceinline__ float ldv_rw(const void* p, int i, int f32m){
  if (f32m) return ((const float*)p)[i];
  return b2f_rw(((const __hip_bfloat16*)p)[i]);
}

// ---------------- workspace layout (float offsets) ----------------
#define FLAGS_OFF 0
#define LOSS_OFF  4
#define STATS_OFF 8
#define CB32_OFF  128        // 1024x32 f32
#define CBN_OFF   32896      // 1024
#define IDXP_OFF  33984      // 131072 int
#define IDXN_OFF  165056     // 131072 int
#define R2_OFF    296192     // lnp -> hcat_p accum (524288)
#define R3_OFF    820480     // lnn -> hcat_n accum (524288)
#define R1_OFF    1344768    // h (1048576) / z chunks (CS*262144)

// ---------------- input dtype probe + zero accumulators ----------------
__global__ __launch_bounds__(256) void detect_rw(const void* cbv, float* flags, float* lossacc){
  __shared__ int bad;
  if (threadIdx.x == 0) bad = 0;
  __syncthreads();
  const unsigned short* u = (const unsigned short*)cbv;
  int local = 0;
  for (int i = threadIdx.x; i < 32768; i += 256){
    unsigned e = (u[i] >> 7) & 0xFF;
    if (e >= 126) local = 1;
  }
  if (local) bad = 1;
  __syncthreads();
  if (threadIdx.x == 0){
    flags[0] = bad ? 1.f : 0.f;   // 1.0 => inputs are f32
    lossacc[0] = 0.f; lossacc[1] = 0.f;
  }
}

// ---------------- codebook -> f32 + |c|^2 ----------------
__global__ __launch_bounds__(256) void cbprep_rw(const void* cbv, const float* flags,
                                                 float* cb32, float* cbn){
  const int f32m = (flags[0] != 0.f);
  int j = blockIdx.x * 256 + threadIdx.x;
  if (j < 1024){
    float s = 0.f;
    for (int e = 0; e < 32; ++e){
      float v = ldv_rw(cbv, j*32 + e, f32m);
      cb32[j*32 + e] = v;
      s += v*v;
    }
    cbn[j] = s;
  }
}

// ---------------- gemm2 (r11, verified): 32px x 64out tiles ----------------
template<int KCH, int INMODE, bool OUTSILU, bool ATOMIC, int LEVELS>
__global__ __launch_bounds__(256) void gemm2_rw(
    const float* __restrict__ inF, const float* __restrict__ inF2,
    const void* __restrict__ inV,
    const void* __restrict__ W, const void* __restrict__ biasO,
    const void* __restrict__ sbA, const void* __restrict__ sbB,
    const int* __restrict__ idxin, const float* __restrict__ cb32,
    float* __restrict__ outF, const float* __restrict__ flags,
    int KDIM, int OUTC, int o_off, int b_base, int ib_sub, int ob_sub)
{
  __shared__ float As[32][32];
  __shared__ float Bs[32][68];
  __shared__ int   IdxS[32][32];

  const int f32m = (flags[0] != 0.f);
  const int t  = threadIdx.x;
  const int q0 = (blockIdx.x << 5) + (b_base << 8);
  const int b  = q0 >> 8;
  const int p0 = q0 & 255;
  const int o0 = blockIdx.y << 6;
  const int k0base = blockIdx.z * KCH;
  const int tx = t & 15, ty = t >> 4;
  float acc[4][2] = {};

  const int sch = t >> 3, spx = (t & 7) << 2;

  if constexpr (INMODE == 3){
    #pragma unroll
    for (int j = 0; j < 4; ++j){
      const int p = p0 + spx + j;
      if constexpr (LEVELS == 4){
        const int l = sch >> 3, kp = sch & 7;
        IdxS[sch][spx + j] = idxin[b*8192 + (((kp << 8) + p) << 2) + l];
      } else {
        IdxS[sch][spx + j] = idxin[b*8192 + (sch << 8) + p];
      }
    }
    __syncthreads();
  }

  for (int kc = 0; kc < KCH; kc += 32){
    const int k0 = k0base + kc;
    if constexpr (INMODE == 0){
      const float4 v = *reinterpret_cast<const float4*>(
          &inF[(((b - ib_sub)*KDIM + k0 + sch) << 8) + p0 + spx]);
      *reinterpret_cast<float4*>(&As[sch][spx]) = v;
    } else if constexpr (INMODE == 2){
      if (f32m){
        const float* xf = (const float*)inV;
        float4 v = *reinterpret_cast<const float4*>(&xf[((b*KDIM + k0 + sch) << 8) + p0 + spx]);
        v.x = silu_rw(v.x); v.y = silu_rw(v.y); v.z = silu_rw(v.z); v.w = silu_rw(v.w);
        *reinterpret_cast<float4*>(&As[sch][spx]) = v;
      } else {
        const __hip_bfloat16* xb = (const __hip_bfloat16*)inV;
        const int off = ((b*KDIM + k0 + sch) << 8) + p0 + spx;
        #pragma unroll
        for (int j = 0; j < 4; ++j) As[sch][spx + j] = silu_rw(b2f_rw(xb[off + j]));
      }
    } else if constexpr (INMODE == 3){
      const int e = k0 >> 5;
      #pragma unroll
      for (int j = 0; j < 4; ++j)
        As[sch][spx + j] = cb32[((IdxS[sch][spx + j] & 1023) << 5) + e];
    } else { // INMODE 5
      const float* src = (k0 < 128) ? inF : inF2;
      const void* sb   = (k0 < 128) ? sbA : sbB;
      const int kh = k0 & 127;
      const float bb = ldv_rw(sb, kh + sch, f32m);
      float4 v = *reinterpret_cast<const float4*>(&src[((b*128 + kh + sch) << 8) + p0 + spx]);
      v.x = silu_rw(v.x + bb); v.y = silu_rw(v.y + bb);
      v.z = silu_rw(v.z + bb); v.w = silu_rw(v.w + bb);
      *reinterpret_cast<float4*>(&As[sch][spx]) = v;
    }
    if (f32m){
      const float* Wf = (const float*)W;
      #pragma unroll
      for (int r = 0; r < 8; ++r){
        int ii = t + (r << 8); int oo = ii >> 5, cc = ii & 31;
        Bs[cc][oo] = Wf[(o0 + oo)*KDIM + k0 + cc];
      }
    } else {
      const __hip_bfloat16* Wb = (const __hip_bfloat16*)W;
      #pragma unroll
      for (int r = 0; r < 8; ++r){
        int ii = t + (r << 8); int oo = ii >> 5, cc = ii & 31;
        Bs[cc][oo] = b2f_rw(Wb[(o0 + oo)*KDIM + k0 + cc]);
      }
    }
    __syncthreads();
    #pragma unroll
    for (int kk = 0; kk < 32; ++kk){
      const float2 a = *reinterpret_cast<const float2*>(&As[kk][tx << 1]);
      const float4 w = *reinterpret_cast<const float4*>(&Bs[kk][ty << 2]);
      acc[0][0] += w.x*a.x; acc[0][1] += w.x*a.y;
      acc[1][0] += w.y*a.x; acc[1][1] += w.y*a.y;
      acc[2][0] += w.z*a.x; acc[2][1] += w.z*a.y;
      acc[3][0] += w.w*a.x; acc[3][1] += w.w*a.y;
    }
    __syncthreads();
  }
  #pragma unroll
  for (int i = 0; i < 4; ++i){
    const int o = o0 + (ty << 2) + i;
    const int base = (((b - ob_sub)*OUTC + o_off + o) << 8) + p0 + (tx << 1);
    if constexpr (ATOMIC){
      atomicAdd(&outF[base + 0], acc[i][0]);
      atomicAdd(&outF[base + 1], acc[i][1]);
    } else {
      const float bb = ldv_rw(biasO, o, f32m);
      float v0 = acc[i][0] + bb, v1 = acc[i][1] + bb;
      if constexpr (OUTSILU){ v0 = silu_rw(v0); v1 = silu_rw(v1); }
      *reinterpret_cast<float2*>(&outF[base]) = make_float2(v0, v1);
    }
  }
}

// ---------------- per-sample LN stats over silu(h_half) ----------------
__global__ __launch_bounds__(256) void stats_rw(const float* __restrict__ h, float* __restrict__ stats){
  const int b = blockIdx.x >> 1, half = blockIdx.x & 1;
  const float* base = h + ((b*256 + half*128) << 8);
  float s = 0.f, s2 = 0.f;
  for (int i = threadIdx.x; i < 32768; i += 256){
    float a = silu_rw(base[i]);
    s += a; s2 += a*a;
  }
  __shared__ float sh[2][256];
  sh[0][threadIdx.x] = s; sh[1][threadIdx.x] = s2;
  __syncthreads();
  for (int st = 128; st > 0; st >>= 1){
    if (threadIdx.x < st){
      sh[0][threadIdx.x] += sh[0][threadIdx.x + st];
      sh[1][threadIdx.x] += sh[1][threadIdx.x + st];
    }
    __syncthreads();
  }
  if (threadIdx.x == 0){
    float mu  = sh[0][0] * (1.f/32768.f);
    float var = sh[1][0] * (1.f/32768.f) - mu*mu;
    stats[half*32 + b]      = mu;
    stats[half*32 + 16 + b] = 1.f / sqrtf(var + 1e-5f);
  }
}

// ---------------- LN apply ----------------
__global__ __launch_bounds__(256) void ln_rw(const float* __restrict__ h,
    const void* lwp, const void* lbp, const void* lwn, const void* lbn,
    const float* __restrict__ stats, const float* __restrict__ flags,
    float* __restrict__ lnp, float* __restrict__ lnn){
  const int f32m = (flags[0] != 0.f);
  int i = blockIdx.x * 256 + threadIdx.x;
  int b = i >> 16, c = (i >> 8) & 255, p = i & 255;
  float a = silu_rw(h[i]);
  if (c < 128){
    float v = (a - stats[b]) * stats[16 + b] * ldv_rw(lwp, (c << 8) + p, f32m) + ldv_rw(lbp, (c << 8) + p, f32m);
    lnp[((b*128 + c) << 8) + p] = v;
  } else {
    int cc = c - 128;
    float v = (a - stats[32 + b]) * stats[48 + b] * ldv_rw(lwn, (cc << 8) + p, f32m) + ldv_rw(lbn, (cc << 8) + p, f32m);
    lnn[((b*128 + cc) << 8) + p] = v;
  }
}

// ---------------- VQ search v3: 8-way code split + bank-skewed LDS ----------------
// pt = gid&7 scans, per 256-code tile t, the stripe jl = pt*32 + i (i<32):
// j = t*256 + pt*32 + i, ascending within part. VPT=2 (vid0, vid0+CS*4096).
// Skew: cbT stored at idx+(idx>>8) (float4), read at jl*8+e4+(jl>>5) -> the 8
// parts hit 8 disjoint 4-bank groups. cbnS at j+(j>>5) -> 8 distinct banks.
// 8-lane shfl combine with (d, j) lexicographic min == np first-argmin.
template<int LEVELS>
__global__ __launch_bounds__(256) void quant_rw(const float* __restrict__ z,
    const float* __restrict__ cb32, const float* __restrict__ cbn,
    int* __restrict__ idxout, float* __restrict__ lossacc, int b_base, int CS){
  __shared__ float4 cbT[2056];     // 2048 + skew holes
  __shared__ float  cbnS[1056];    // 1024 + skew holes
  __shared__ float  red[256];

  const int tid = threadIdx.x;
  const int gid = blockIdx.x * 256 + tid;
  const int pt = gid & 7;
  const int vbase = gid >> 3;
  const int halfstride = CS << 12;             // CS*4096
  const int vid0 = vbase, vid1 = vbase + halfstride;

  const int bl0 = vid0 >> 13, bl1 = vid1 >> 13;
  const int w = vid0 & 8191;
  int p, cbase;
  if (LEVELS == 4){
    int l = w & 3, n = w >> 2;
    p = n & 255; cbase = (l << 3) + (n >> 8);
  } else {
    p = w & 255; cbase = w >> 8;
  }

  // stage |c|^2 with skew
  #pragma unroll
  for (int q = 0; q < 4; ++q){
    const int i = tid + (q << 8);
    cbnS[i + (i >> 5)] = cbn[i];
  }

  float4 za[8], zb[8];
  float zn0 = 0.f, zn1 = 0.f;
  const int zoff = ((bl0 << 10) + cbase) << 8;
  const int zoff1 = ((bl1 << 10) + cbase) << 8;
  #pragma unroll
  for (int e4 = 0; e4 < 8; ++e4){
    float4 a, b;
    a.x = z[zoff  + (((e4<<2)+0) << 13) + p];
    a.y = z[zoff  + (((e4<<2)+1) << 13) + p];
    a.z = z[zoff  + (((e4<<2)+2) << 13) + p];
    a.w = z[zoff  + (((e4<<2)+3) << 13) + p];
    b.x = z[zoff1 + (((e4<<2)+0) << 13) + p];
    b.y = z[zoff1 + (((e4<<2)+1) << 13) + p];
    b.z = z[zoff1 + (((e4<<2)+2) << 13) + p];
    b.w = z[zoff1 + (((e4<<2)+3) << 13) + p];
    za[e4] = a; zb[e4] = b;
    zn0 += a.x*a.x; zn0 += a.y*a.y; zn0 += a.z*a.z; zn0 += a.w*a.w;
    zn1 += b.x*b.x; zn1 += b.y*b.y; zn1 += b.z*b.z; zn1 += b.w*b.w;
  }

  float best0 = __builtin_inff(), best1 = __builtin_inff();
  int bi0 = 0, bi1 = 0;

  const int jl0 = pt << 5;                     // this part's stripe base
  for (int t = 0; t < 4; ++t){
    __syncthreads();
    // stage tile t (2048 float4, skewed)
    const float4* g4 = reinterpret_cast<const float4*>(cb32) + (t << 11);
    #pragma unroll
    for (int r = 0; r < 8; ++r){
      const int idx = tid + (r << 8);
      cbT[idx + (idx >> 8)] = g4[idx];
    }
    __syncthreads();

    #pragma unroll 4
    for (int i = 0; i < 32; ++i){
      const int jl = jl0 + i;
      const int j  = (t << 8) + jl;
      const float4* c = &cbT[(jl << 3) + (jl >> 5)];
      float dot0 = 0.f, dot1 = 0.f;
      #pragma unroll
      for (int e4 = 0; e4 < 8; ++e4){
        const float4 cc = c[e4];
        dot0 = fmaf(za[e4].x, cc.x, dot0); dot1 = fmaf(zb[e4].x, cc.x, dot1);
        dot0 = fmaf(za[e4].y, cc.y, dot0); dot1 = fmaf(zb[e4].y, cc.y, dot1);
        dot0 = fmaf(za[e4].z, cc.z, dot0); dot1 = fmaf(zb[e4].z, cc.z, dot1);
        dot0 = fmaf(za[e4].w, cc.w, dot0); dot1 = fmaf(zb[e4].w, cc.w, dot1);
      }
      const float cn = cbnS[j + (j >> 5)];
      const float d0 = (zn0 - 2.f*dot0) + cn;
      const float d1 = (zn1 - 2.f*dot1) + cn;
      if (d0 < best0){ best0 = d0; bi0 = j; }
      if (d1 < best1){ best1 = d1; bi1 = j; }
    }
  }

  // combine the 8 parts (lanes gid&7): lexicographic (d, j) min
  #pragma unroll
  for (int k = 4; k > 0; k >>= 1){
    float od0 = __shfl_down(best0, k); int oj0 = __shfl_down(bi0, k);
    float od1 = __shfl_down(best1, k); int oj1 = __shfl_down(bi1, k);
    if (od0 < best0 || (od0 == best0 && oj0 < bi0)){ best0 = od0; bi0 = oj0; }
    if (od1 < best1 || (od1 == best1 && oj1 < bi1)){ best1 = od1; bi1 = oj1; }
  }
  if (pt == 0){
    idxout[(b_base + bl0)*8192 + w] = bi0;
    idxout[(b_base + bl1)*8192 + w] = bi1;
  }
  red[tid] = (pt == 0) ? (best0 + best1) : 0.f;
  __syncthreads();
  for (int st = 128; st > 0; st >>= 1){
    if (tid < st) red[tid] += red[tid + st];
    __syncthreads();
  }
  if (tid == 0) atomicAdd(lossacc, red[0]);
}

// ---------------- zq_p output (f32) ----------------
__global__ __launch_bounds__(256) void zqout_rw(const int* __restrict__ idxp,
    const float* __restrict__ cb32, float* __restrict__ out){
  int t = blockIdx.x * 256 + threadIdx.x;
  int l = t & 3, n = (t >> 2) & 2047, e = (t >> 13) & 31, b = t >> 18;
  int id = idxp[b*8192 + (n << 2) + l];
  out[t] = cb32[((id & 1023) << 5) + e];
}

// ---------------- zero hcat accum ----------------
__global__ __launch_bounds__(256) void zero_rw(float* __restrict__ p){
  p[blockIdx.x * 256 + threadIdx.x] = 0.f;
}

// ---------------- loss finalize ----------------
__global__ void loss_rw(const float* __restrict__ lossacc, float* __restrict__ out){
  if (threadIdx.x == 0 && blockIdx.x == 0)
    out[0] = 1.25f * (lossacc[0] + lossacc[1]) * (1.f/4194304.f);
}

extern "C" void kernel_launch(void* const* d_in, const int* in_sizes, int n_in,
                              void* d_out, int out_size, void* d_ws, size_t ws_size,
                              hipStream_t stream){
  (void)in_sizes; (void)n_in; (void)out_size;
  const void* x   = d_in[0];
  const void* ciw = d_in[1];
  const void* cib = d_in[2];
  const void* lwp = d_in[3];
  const void* lbp = d_in[4];
  const void* wpi = d_in[5];
  const void* bpi = d_in[6];
  const void* wpo = d_in[7];
  const void* bpo = d_in[8];
  const void* lwn = d_in[9];
  const void* lbn = d_in[10];
  const void* wni = d_in[11];
  const void* bni = d_in[12];
  const void* wno = d_in[13];
  const void* bno = d_in[14];
  const void* cbk = d_in[15];
  const void* cow = d_in[16];
  const void* cob = d_in[17];

  float* ws    = (float*)d_ws;
  float* flags = ws + FLAGS_OFF;
  float* loss  = ws + LOSS_OFF;
  float* stats = ws + STATS_OFF;
  float* cb32  = ws + CB32_OFF;
  float* cbn   = ws + CBN_OFF;
  int*   idxp  = (int*)(ws + IDXP_OFF);
  int*   idxn  = (int*)(ws + IDXN_OFF);
  float* R2    = ws + R2_OFF;
  float* R3    = ws + R3_OFF;
  float* R1    = ws + R1_OFF;

  float* outO = (float*)d_out;
  float* outL = outO + 1048576;
  float* outZ = outO + 1048577;

  const size_t wsf = ws_size / 4;
  int CS = 4;
  if      (wsf >= (size_t)R1_OFF + 16u*262144u) CS = 16;
  else if (wsf >= (size_t)R1_OFF +  8u*262144u) CS = 8;

  detect_rw<<<1, 256, 0, stream>>>(cbk, flags, loss);
  cbprep_rw<<<4, 256, 0, stream>>>(cbk, flags, cb32, cbn);
  // h = conv_in(silu(x)) -> R1
  gemm2_rw<256,2,false,false,0><<<dim3(128,4), 256, 0, stream>>>(
      nullptr, nullptr, x, ciw, cib, nullptr, nullptr, nullptr, nullptr,
      R1, flags, 256, 256, 0, 0, 0, 0);
  stats_rw<<<32, 256, 0, stream>>>(R1, stats);
  ln_rw<<<4096, 256, 0, stream>>>(R1, lwp, lbp, lwn, lbn, stats, flags, R2, R3);
  // phylo: z chunks (R2 -> R1), quantize (grid CS*128 = 512 blocks at CS=4)
  for (int c = 0; c < 16; c += CS){
    gemm2_rw<128,0,true,false,0><<<dim3(CS*8,16), 256, 0, stream>>>(
        R2, nullptr, nullptr, wpi, bpi, nullptr, nullptr, nullptr, nullptr,
        R1, flags, 128, 1024, 0, c, 0, c);
    quant_rw<4><<<CS*128, 256, 0, stream>>>(R1, cb32, cbn, idxp, loss + 0, c, CS);
  }
  // non-phylo
  for (int c = 0; c < 16; c += CS){
    gemm2_rw<128,0,true,false,0><<<dim3(CS*8,16), 256, 0, stream>>>(
        R3, nullptr, nullptr, wni, bni, nullptr, nullptr, nullptr, nullptr,
        R1, flags, 128, 1024, 0, c, 0, c);
    quant_rw<1><<<CS*128, 256, 0, stream>>>(R1, cb32, cbn, idxn, loss + 1, c, CS);
  }
  zqout_rw<<<16384, 256, 0, stream>>>(idxp, cb32, outZ);
  // hcat accum := 0
  zero_rw<<<4096, 256, 0, stream>>>(R2);
  // hout_p / hout_n: fused gather + split-K x4, atomic accum
  gemm2_rw<256,3,false,true,4><<<dim3(128,2,4), 256, 0, stream>>>(
      nullptr, nullptr, nullptr, wpo, nullptr, nullptr, nullptr, idxp, cb32,
      R2, flags, 1024, 128, 0, 0, 0, 0);
  gemm2_rw<256,3,false,true,1><<<dim3(128,2,4), 256, 0, stream>>>(
      nullptr, nullptr, nullptr, wno, nullptr, nullptr, nullptr, idxn, cb32,
      R3, flags, 1024, 128, 0, 0, 0, 0);
  // out = conv_out(silu(hcat + hout_bias))
  gemm2_rw<256,5,false,false,0><<<dim3(128,4), 256, 0, stream>>>(
      R2, R3, nullptr, cow, cob, bpo, bno, nullptr, nullptr,
      outO, flags, 256, 256, 0, 0, 0, 0);
  loss_rw<<<1, 64, 0, stream>>>(loss, outL);
}